// Round 2
// baseline (290.017 us; speedup 1.0000x reference)
//
#include <hip/hip_runtime.h>

// MeanAggregator: out[b,:] = mean over DISTINCT nbrs[b,:] of features[idx,:]
// features: [N=200000, D=256] f32; nbrs: [B=32768, S=10] int32; out: [B,256] f32
//
// Round 2: 4 rows per wave (quarter-wave per row) to quadruple per-wave MLP.
//   lane = 16*g + t;  group g in [0,4) owns row waveId*4+g, sublane t in [0,16).
//   A gather of one feature row = 4 loads of float4 per lane:
//     column floats [q*64 + t*4, ... +4) for q=0..3  -> each instruction covers
//     a contiguous 256B segment per row-group (16 lanes x 16B), 4 rows/instr.
//   Up to 40 independent gather loads in flight per wave (vs 10 in round 1).
// Dedupe (first-occurrence-only weights) computed per-lane in registers,
// branchless, identical math to the reference.

#define AGG_S 10
#define AGG_D 256

__global__ __launch_bounds__(256) void MeanAggregator_58514634441194_kernel(
    const float* __restrict__ feat,
    const int* __restrict__ nbrs,
    float* __restrict__ out,
    int B)
{
    const int waveId = (blockIdx.x * blockDim.x + threadIdx.x) >> 6;
    const int lane   = threadIdx.x & 63;
    const int g      = lane >> 4;    // which of the wave's 4 rows
    const int t      = lane & 15;    // sublane within the row's 16 lanes

    const int rowId = waveId * 4 + g;
    if (rowId >= B) return;

    // 10 neighbor indices for this group's row (same addr across 16 lanes).
    const int* __restrict__ row = nbrs + (size_t)rowId * AGG_S;
    int idx[AGG_S];
#pragma unroll
    for (int s = 0; s < AGG_S; ++s) idx[s] = row[s];

    // First-occurrence weights: w[s]=0 iff idx[s] appeared at some j<s.
    float w[AGG_S];
    float cnt = 0.0f;
#pragma unroll
    for (int s = 0; s < AGG_S; ++s) {
        bool dup = false;
#pragma unroll
        for (int j = 0; j < AGG_S; ++j) {
            if (j < s) dup |= (idx[j] == idx[s]);
        }
        w[s] = dup ? 0.0f : 1.0f;
        cnt += w[s];
    }

    // Gather + weighted accumulate. 40 independent float4 loads per wave.
    float4 acc[4];
#pragma unroll
    for (int q = 0; q < 4; ++q) acc[q] = make_float4(0.f, 0.f, 0.f, 0.f);

#pragma unroll
    for (int s = 0; s < AGG_S; ++s) {
        const float* __restrict__ fr = feat + (size_t)idx[s] * AGG_D;
#pragma unroll
        for (int q = 0; q < 4; ++q) {
            float4 v = ((const float4*)(fr + q * 64))[t];
            acc[q].x += w[s] * v.x;
            acc[q].y += w[s] * v.y;
            acc[q].z += w[s] * v.z;
            acc[q].w += w[s] * v.w;
        }
    }

    const float inv = 1.0f / cnt;
    float* __restrict__ orow = out + (size_t)rowId * AGG_D;
#pragma unroll
    for (int q = 0; q < 4; ++q) {
        float4 r = acc[q];
        r.x *= inv; r.y *= inv; r.z *= inv; r.w *= inv;
        ((float4*)(orow + q * 64))[t] = r;
    }
}

extern "C" void kernel_launch(void* const* d_in, const int* in_sizes, int n_in,
                              void* d_out, int out_size, void* d_ws, size_t ws_size,
                              hipStream_t stream)
{
    const float* feat = (const float*)d_in[0];
    const int*   nbrs = (const int*)d_in[1];
    float*       out  = (float*)d_out;

    const int B = in_sizes[1] / AGG_S;                 // 32768
    const int waves = (B + 3) / 4;                     // 4 rows per wave
    const int threads = 256;                           // 4 waves per block
    const int blocks = (waves + 3) / 4;

    MeanAggregator_58514634441194_kernel<<<blocks, threads, 0, stream>>>(
        feat, nbrs, out, B);
}

// Round 4
// 287.956 us; speedup vs baseline: 1.0072x; 1.0072x over previous
//
#include <hip/hip_runtime.h>

// MeanAggregator: out[b,:] = mean over DISTINCT nbrs[b,:] of features[idx,:]
// features: [N=200000, D=256] f32; nbrs: [B=32768, S=10] int32; out: [B,256] f32
//
// Round 4: round-3 plan with the compile fix — use a native clang vector type
// for the nontemporal builtins (HIP's float4 is a class; the builtin wants a
// true vector). Layout: 1 wave per row, 16B/lane => one fully-coalesced 1KB
// instruction per gather. nt-store for write-once out, nt-load for read-once
// nbrs, so the 200MB feature table stays LLC-resident (~1.64x reuse).
// Dedupe (first-occurrence weights) branchless in registers.

#define AGG_S 10
#define AGG_D 256

typedef float vfloat4 __attribute__((ext_vector_type(4)));

__global__ __launch_bounds__(256) void MeanAggregator_58514634441194_kernel(
    const float* __restrict__ feat,
    const int* __restrict__ nbrs,
    float* __restrict__ out,
    int B)
{
    const int wave = (blockIdx.x * blockDim.x + threadIdx.x) >> 6;  // row id
    const int lane = threadIdx.x & 63;
    if (wave >= B) return;

    // Row's 10 neighbor indices (wave-uniform address -> broadcast).
    const int* __restrict__ row = nbrs + (size_t)wave * AGG_S;
    int idx[AGG_S];
#pragma unroll
    for (int s = 0; s < AGG_S; ++s) idx[s] = __builtin_nontemporal_load(row + s);

    // First-occurrence weights: w[s]=0 iff idx[s] appeared at some j<s.
    float w[AGG_S];
    float cnt = 0.0f;
#pragma unroll
    for (int s = 0; s < AGG_S; ++s) {
        bool dup = false;
#pragma unroll
        for (int j = 0; j < AGG_S; ++j) {
            if (j < s) dup |= (idx[j] == idx[s]);
        }
        w[s] = dup ? 0.0f : 1.0f;
        cnt += w[s];
    }

    // Gather + weighted accumulate: 10 independent 1KB wave reads.
    vfloat4 acc = (vfloat4)(0.0f);
#pragma unroll
    for (int s = 0; s < AGG_S; ++s) {
        const vfloat4* __restrict__ fr =
            (const vfloat4*)(feat + (size_t)idx[s] * AGG_D);
        vfloat4 v = fr[lane];
        acc += w[s] * v;
    }

    acc *= (1.0f / cnt);

    // Write-once output: nontemporal so it doesn't evict feature lines.
    vfloat4* __restrict__ orow = (vfloat4*)(out + (size_t)wave * AGG_D);
    __builtin_nontemporal_store(acc, orow + lane);
}

extern "C" void kernel_launch(void* const* d_in, const int* in_sizes, int n_in,
                              void* d_out, int out_size, void* d_ws, size_t ws_size,
                              hipStream_t stream)
{
    const float* feat = (const float*)d_in[0];
    const int*   nbrs = (const int*)d_in[1];
    float*       out  = (float*)d_out;

    const int B = in_sizes[1] / AGG_S;           // 32768
    const int threads = 256;                     // 4 waves/block, 1 row/wave
    const int rows_per_block = threads / 64;
    const int blocks = (B + rows_per_block - 1) / rows_per_block;

    MeanAggregator_58514634441194_kernel<<<blocks, threads, 0, stream>>>(
        feat, nbrs, out, B);
}